// Round 1
// baseline (9134.503 us; speedup 1.0000x reference)
//
#include <hip/hip_runtime.h>
#include <hip/hip_bf16.h>
#include <stdint.h>

// ---- model dims (ViT-Base/16, B=32) ----
#define L_DEPTH 12
#define DM      768
#define NHEAD   12
#define DK      64
#define DMLP    3072
#define BB      32
#define NTOK    197
#define NPATCH  196
#define MTOK    (BB*NTOK)     // 6304
#define MPAD    6400          // padded to 128 multiple
#define MPE     (BB*NPATCH)   // 6272 = 49*128

typedef __attribute__((ext_vector_type(8))) short short8;
typedef __attribute__((ext_vector_type(4))) float f4;

__device__ __forceinline__ float bf2f(unsigned short u) {
    union { float f; unsigned int i; } v; v.i = ((unsigned int)u) << 16; return v.f;
}
__device__ __forceinline__ unsigned short f2bf(float f) {
    union { float f; unsigned int i; } v; v.f = f;
    unsigned int i = v.i;
    i += 0x7fffu + ((i >> 16) & 1u);   // round-to-nearest-even
    return (unsigned short)(i >> 16);
}
__device__ __forceinline__ float gelu_f(float x) {
    return 0.5f * x * (1.0f + erff(x * 0.7071067811865475f));
}

// ---------------------------------------------------------------------------
// fp32 -> bf16 flat convert
__global__ void cvt_bf16(const float* __restrict__ src, unsigned short* __restrict__ dst, int n) {
    int i = blockIdx.x * 256 + threadIdx.x;
    if (i < n) dst[i] = f2bf(src[i]);
}

// transpose-convert: src fp32 [K][Nsrc] (per layer, z=layer) -> dst bf16 rows
// [row_off, row_off+Nsrc) of a [Ntot][K] matrix (per layer stride Ntot*K).
__global__ void tconv(const float* __restrict__ src, unsigned short* __restrict__ dst,
                      int K, int Nsrc, int row_off, int Ntot) {
    const int l = blockIdx.z;
    src += (size_t)l * K * Nsrc;
    dst += (size_t)l * Ntot * K + (size_t)row_off * K;
    __shared__ float t[32][33];
    const int tid = threadIdx.x;
    const int tx = tid & 31, ty = tid >> 5;          // 32 x 8
    const int n0 = blockIdx.x * 32, k0 = blockIdx.y * 32;
#pragma unroll
    for (int u = 0; u < 4; ++u) {
        int k = k0 + ty + u * 8;
        t[ty + u * 8][tx] = src[(size_t)k * Nsrc + n0 + tx];
    }
    __syncthreads();
#pragma unroll
    for (int u = 0; u < 4; ++u) {
        int n = n0 + ty + u * 8;
        dst[(size_t)n * K + k0 + tx] = f2bf(t[tx][ty + u * 8]);
    }
}

// im2col for patch embed: A[row= b*196+p][k= c*256+i*16+j] = x[b][c][py*16+i][px*16+j]
__global__ void im2col_k(const float* __restrict__ x, unsigned short* __restrict__ A) {
    int idx = blockIdx.x * 256 + threadIdx.x;          // < 6272*768
    int k = idx % DM, row = idx / DM;
    int b = row / NPATCH, p = row % NPATCH;
    int py = p / 14, px = p % 14;
    int c = k >> 8, rem = k & 255, i = rem >> 4, j = rem & 15;
    float v = x[(((size_t)b * 3 + c) * 224 + py * 16 + i) * 224 + px * 16 + j];
    A[idx] = f2bf(v);
}

// tok[b][n][d] = (n==0 ? cls : pe[b*196+n-1]) + pos[n]
__global__ void assemble_tok(const float* __restrict__ pe, const float* __restrict__ cls_t,
                             const float* __restrict__ pos, float* __restrict__ tok) {
    int idx = blockIdx.x * 256 + threadIdx.x;          // < 6304*768
    int d = idx % DM, row = idx / DM;
    int b = row / NTOK, n = row % NTOK;
    float v = (n == 0) ? cls_t[d] : pe[((size_t)b * NPATCH + n - 1) * DM + d];
    tok[idx] = v + pos[(size_t)n * DM + d];
}

// ---------------------------------------------------------------------------
// 128x128 bf16 MFMA GEMM, BK=32, 4 waves, 4x4 mfma_f32_16x16x32_bf16 per wave.
// A [M][K] bf16 row-major, Bt [N][K] bf16 row-major (= B transposed).
// EPI: 0 plain->bf16 ; 1 bias+gelu->bf16 ; 2 bias+res->fp32 ; 3 bias+gelu->fp32
template <int EPI>
__global__ __launch_bounds__(256, 2)
void gemm128(const unsigned short* __restrict__ A, const unsigned short* __restrict__ Bt,
             const float* __restrict__ bias, const float* res,
             void* Cout, int M, int N, int K) {
    __shared__ __align__(16) unsigned short As[128 * 32];
    __shared__ __align__(16) unsigned short Bs[128 * 32];
    const int tid = threadIdx.x;
    const int lane = tid & 63, wave = tid >> 6;
    const int wm = wave >> 1, wn = wave & 1;
    const int lr = lane & 15, quad = lane >> 4;
    const int bm = blockIdx.y * 128, bn = blockIdx.x * 128;

    f4 acc[4][4];
#pragma unroll
    for (int i = 0; i < 4; ++i)
#pragma unroll
        for (int j = 0; j < 4; ++j) acc[i][j] = (f4){0.f, 0.f, 0.f, 0.f};

    for (int k0 = 0; k0 < K; k0 += 32) {
#pragma unroll
        for (int u = 0; u < 2; ++u) {
            int c = tid + u * 256;               // 512 16B-chunks per 8KB tile
            int row = c >> 2, kc = c & 3;
            *(short8*)&As[c * 8] = *(const short8*)(A + (size_t)(bm + row) * K + k0 + kc * 8);
            *(short8*)&Bs[c * 8] = *(const short8*)(Bt + (size_t)(bn + row) * K + k0 + kc * 8);
        }
        __syncthreads();
        short8 af[4], bfr[4];
#pragma unroll
        for (int i = 0; i < 4; ++i)
            af[i] = *(const short8*)&As[(wm * 64 + i * 16 + lr) * 32 + quad * 8];
#pragma unroll
        for (int j = 0; j < 4; ++j)
            bfr[j] = *(const short8*)&Bs[(wn * 64 + j * 16 + lr) * 32 + quad * 8];
#pragma unroll
        for (int i = 0; i < 4; ++i)
#pragma unroll
            for (int j = 0; j < 4; ++j)
                acc[i][j] = __builtin_amdgcn_mfma_f32_16x16x32_bf16(af[i], bfr[j], acc[i][j], 0, 0, 0);
        __syncthreads();
    }

#pragma unroll
    for (int i = 0; i < 4; ++i)
#pragma unroll
        for (int j = 0; j < 4; ++j)
#pragma unroll
            for (int r = 0; r < 4; ++r) {
                int row = bm + wm * 64 + i * 16 + quad * 4 + r;
                int col = bn + wn * 64 + j * 16 + lr;
                float v = acc[i][j][r];
                if (EPI == 1 || EPI == 2 || EPI == 3) v += bias[col];
                if (EPI == 1 || EPI == 3) v = gelu_f(v);
                if (EPI == 2) v += res[(size_t)row * N + col];
                if (EPI == 0 || EPI == 1)
                    ((unsigned short*)Cout)[(size_t)row * N + col] = f2bf(v);
                else
                    ((float*)Cout)[(size_t)row * N + col] = v;
            }
}

// ---------------------------------------------------------------------------
// LayerNorm (768) fp32 in -> bf16 out, one block per row
__global__ __launch_bounds__(256)
void ln_bf16(const float* __restrict__ x, const float* __restrict__ w,
             const float* __restrict__ b, unsigned short* __restrict__ out) {
    __shared__ float red[8];
    const int tid = threadIdx.x;
    const size_t row = blockIdx.x;
    const float* xr = x + row * DM;
    float v0 = xr[tid], v1 = xr[tid + 256], v2 = xr[tid + 512];
    float s = v0 + v1 + v2, s2 = v0 * v0 + v1 * v1 + v2 * v2;
    for (int o = 32; o > 0; o >>= 1) { s += __shfl_down(s, o); s2 += __shfl_down(s2, o); }
    if ((tid & 63) == 0) { red[(tid >> 6) * 2] = s; red[(tid >> 6) * 2 + 1] = s2; }
    __syncthreads();
    s = red[0] + red[2] + red[4] + red[6];
    s2 = red[1] + red[3] + red[5] + red[7];
    float mean = s * (1.f / DM);
    float rstd = rsqrtf(s2 * (1.f / DM) - mean * mean + 1e-5f);
    out[row * DM + tid]       = f2bf((v0 - mean) * rstd * w[tid]       + b[tid]);
    out[row * DM + tid + 256] = f2bf((v1 - mean) * rstd * w[tid + 256] + b[tid + 256]);
    out[row * DM + tid + 512] = f2bf((v2 - mean) * rstd * w[tid + 512] + b[tid + 512]);
}

// ---------------------------------------------------------------------------
// attention: scores (QK^T * scale) + softmax for a 32-row tile of one (b,h)
#define PSTR 208   // probs row stride (bf16 elements)
__global__ __launch_bounds__(256)
void attn_softmax(const unsigned short* __restrict__ qkv, unsigned short* __restrict__ probs) {
    __shared__ float Qs[32 * 64];
    __shared__ unsigned short Ks[197 * 64];
    __shared__ float Ss[32 * 200];
    const int tid = threadIdx.x;
    const int rt = blockIdx.x;                // 0..6
    const int bh = blockIdx.y;                // 0..383
    const int b = bh / NHEAD, hh = bh % NHEAD;
    const size_t base = ((size_t)b * NTOK) * 2304 + hh * 64;
    for (int e = tid; e < 32 * 64; e += 256) {
        int r = e >> 6, d = e & 63;
        int n = rt * 32 + r;
        float q = 0.f;
        if (n < NTOK) q = bf2f(qkv[base + (size_t)n * 2304 + d]);
        Qs[e] = q * 0.125f;                   // 1/sqrt(64)
    }
    for (int e = tid; e < 197 * 64; e += 256) {
        int m = e >> 6, d = e & 63;
        Ks[e] = qkv[base + 768 + (size_t)m * 2304 + d];
    }
    __syncthreads();
    const int r = tid >> 3, jj = tid & 7;
    const float* qrow = &Qs[r * 64];
    for (int m = jj; m < NTOK; m += 8) {
        const unsigned short* krow = &Ks[m * 64];
        float sc = 0.f;
#pragma unroll
        for (int kk = 0; kk < 64; ++kk) {     // rotate start by lane: kills bank conflicts
            int k = (kk + jj * 8) & 63;
            sc += qrow[k] * bf2f(krow[k]);
        }
        Ss[r * 200 + m] = sc;
    }
    __syncthreads();
    float mx = -1e30f;
    for (int m = jj; m < NTOK; m += 8) mx = fmaxf(mx, Ss[r * 200 + m]);
    mx = fmaxf(mx, __shfl_xor(mx, 1, 8));
    mx = fmaxf(mx, __shfl_xor(mx, 2, 8));
    mx = fmaxf(mx, __shfl_xor(mx, 4, 8));
    float sum = 0.f;
    for (int m = jj; m < NTOK; m += 8) {
        float e = __expf(Ss[r * 200 + m] - mx);
        Ss[r * 200 + m] = e; sum += e;
    }
    sum += __shfl_xor(sum, 1, 8);
    sum += __shfl_xor(sum, 2, 8);
    sum += __shfl_xor(sum, 4, 8);
    float inv = 1.f / sum;
    int n = rt * 32 + r;
    if (n < NTOK) {
        unsigned short* prow = probs + ((size_t)bh * NTOK + n) * PSTR;
        for (int m = jj; m < NTOK; m += 8) prow[m] = f2bf(Ss[r * 200 + m] * inv);
    }
}

// ctx = probs @ V for a 32-row tile of one (b,h); out bf16 into [MPAD][768]
__global__ __launch_bounds__(256)
void attn_ctx(const unsigned short* __restrict__ qkv, const unsigned short* __restrict__ probs,
              unsigned short* __restrict__ ctx) {
    __shared__ unsigned short Vs[197 * 64];
    __shared__ float Ps[32 * 200];
    const int tid = threadIdx.x;
    const int rt = blockIdx.x, bh = blockIdx.y;
    const int b = bh / NHEAD, hh = bh % NHEAD;
    const size_t baseV = ((size_t)b * NTOK) * 2304 + 1536 + hh * 64;
    for (int e = tid; e < 197 * 64; e += 256) {
        int m = e >> 6, d = e & 63;
        Vs[e] = qkv[baseV + (size_t)m * 2304 + d];
    }
    for (int e = tid; e < 32 * 200; e += 256) {
        int r = e / 200, m = e % 200;
        int n = rt * 32 + r;
        float pv = 0.f;
        if (n < NTOK && m < NTOK) pv = bf2f(probs[((size_t)bh * NTOK + n) * PSTR + m]);
        Ps[e] = pv;
    }
    __syncthreads();
    const int r = tid >> 3, d0 = (tid & 7) * 8;
    float a[8] = {0, 0, 0, 0, 0, 0, 0, 0};
    for (int m = 0; m < NTOK; ++m) {
        float pv = Ps[r * 200 + m];
        const unsigned short* vr = &Vs[m * 64 + d0];
#pragma unroll
        for (int u = 0; u < 8; ++u) a[u] += pv * bf2f(vr[u]);
    }
    int n = rt * 32 + r;
    if (n < NTOK) {
        unsigned short* crow = ctx + (size_t)(b * NTOK + n) * DM + hh * 64 + d0;
#pragma unroll
        for (int u = 0; u < 8; ++u) crow[u] = f2bf(a[u]);
    }
}

// ---------------------------------------------------------------------------
// head: fnorm-LN then hln-LN on cls rows -> fp32 [32][768]
__global__ __launch_bounds__(256)
void head_ln(const float* __restrict__ tok, const float* __restrict__ fw, const float* __restrict__ fb,
             const float* __restrict__ hw, const float* __restrict__ hb, float* __restrict__ cls) {
    __shared__ float red[8];
    const int tid = threadIdx.x;
    const float* xr = tok + (size_t)blockIdx.x * NTOK * DM;   // n==0 row
    float v0 = xr[tid], v1 = xr[tid + 256], v2 = xr[tid + 512];
    float s = v0 + v1 + v2, s2 = v0 * v0 + v1 * v1 + v2 * v2;
    for (int o = 32; o > 0; o >>= 1) { s += __shfl_down(s, o); s2 += __shfl_down(s2, o); }
    if ((tid & 63) == 0) { red[(tid >> 6) * 2] = s; red[(tid >> 6) * 2 + 1] = s2; }
    __syncthreads();
    s = red[0] + red[2] + red[4] + red[6];
    s2 = red[1] + red[3] + red[5] + red[7];
    float mean = s * (1.f / DM), rstd = rsqrtf(s2 * (1.f / DM) - mean * mean + 1e-5f);
    v0 = (v0 - mean) * rstd * fw[tid]       + fb[tid];
    v1 = (v1 - mean) * rstd * fw[tid + 256] + fb[tid + 256];
    v2 = (v2 - mean) * rstd * fw[tid + 512] + fb[tid + 512];
    __syncthreads();
    s = v0 + v1 + v2; s2 = v0 * v0 + v1 * v1 + v2 * v2;
    for (int o = 32; o > 0; o >>= 1) { s += __shfl_down(s, o); s2 += __shfl_down(s2, o); }
    if ((tid & 63) == 0) { red[(tid >> 6) * 2] = s; red[(tid >> 6) * 2 + 1] = s2; }
    __syncthreads();
    s = red[0] + red[2] + red[4] + red[6];
    s2 = red[1] + red[3] + red[5] + red[7];
    mean = s * (1.f / DM); rstd = rsqrtf(s2 * (1.f / DM) - mean * mean + 1e-5f);
    float* cr = cls + (size_t)blockIdx.x * DM;
    cr[tid]       = (v0 - mean) * rstd * hw[tid]       + hb[tid];
    cr[tid + 256] = (v1 - mean) * rstd * hw[tid + 256] + hb[tid + 256];
    cr[tid + 512] = (v2 - mean) * rstd * hw[tid + 512] + hb[tid + 512];
}

__global__ __launch_bounds__(256)
void head_mlp1(const float* __restrict__ cls, const float* __restrict__ w,
               const float* __restrict__ bias, float* __restrict__ outv) {
    __shared__ float cl[DM];
    const int tid = threadIdx.x;
    const int b = blockIdx.y;
    const int col = blockIdx.x * 256 + tid;
    for (int e = tid; e < DM; e += 256) cl[e] = cls[(size_t)b * DM + e];
    __syncthreads();
    float s = bias[col];
    for (int k = 0; k < DM; ++k) s += cl[k] * w[(size_t)k * DMLP + col];
    outv[(size_t)b * DMLP + col] = gelu_f(s);
}

__global__ __launch_bounds__(256)
void head_mlp2(const float* __restrict__ midh, const float* __restrict__ w,
               const float* __restrict__ bias, float* __restrict__ out) {
    __shared__ float red[256];
    const int tid = threadIdx.x;
    const int b = blockIdx.x >> 1, c = blockIdx.x & 1;
    float s = 0.f;
    for (int k = tid; k < DMLP; k += 256) s += midh[(size_t)b * DMLP + k] * w[(size_t)k * 2 + c];
    red[tid] = s;
    __syncthreads();
    for (int o = 128; o > 0; o >>= 1) { if (tid < o) red[tid] += red[tid + o]; __syncthreads(); }
    if (tid == 0) out[blockIdx.x] = red[0] + bias[c];
}

// ---------------------------------------------------------------------------
extern "C" void kernel_launch(void* const* d_in, const int* in_sizes, int n_in,
                              void* d_out, int out_size, void* d_ws, size_t ws_size,
                              hipStream_t stream) {
    if (n_in < 26) return;
    const float* x       = (const float*)d_in[0];
    const float* conv_w  = (const float*)d_in[1];
    const float* conv_b  = (const float*)d_in[2];
    const float* cls_tok = (const float*)d_in[3];
    const float* pos     = (const float*)d_in[4];
    const float* ln1_w   = (const float*)d_in[5];
    const float* ln1_b   = (const float*)d_in[6];
    const float* wq      = (const float*)d_in[7];
    const float* wk      = (const float*)d_in[8];
    const float* wv      = (const float*)d_in[9];
    const float* wo_w    = (const float*)d_in[10];
    const float* wo_b    = (const float*)d_in[11];
    const float* ln2_w   = (const float*)d_in[12];
    const float* ln2_b   = (const float*)d_in[13];
    const float* mlp1_w  = (const float*)d_in[14];
    const float* mlp1_b  = (const float*)d_in[15];
    const float* mlp2_w  = (const float*)d_in[16];
    const float* mlp2_b  = (const float*)d_in[17];
    const float* fnorm_w = (const float*)d_in[18];
    const float* fnorm_b = (const float*)d_in[19];
    const float* hln_w   = (const float*)d_in[20];
    const float* hln_b   = (const float*)d_in[21];
    const float* h1_w    = (const float*)d_in[22];
    const float* h1_b    = (const float*)d_in[23];
    const float* h2_w    = (const float*)d_in[24];
    const float* h2_b    = (const float*)d_in[25];

    char* p = (char*)d_ws;
    auto alloc = [&](size_t bytes) -> char* {
        char* r = p; p += (bytes + 255) & ~(size_t)255; return r;
    };
    unsigned short* Wqkv = (unsigned short*)alloc((size_t)L_DEPTH * 2304 * 768 * 2);
    unsigned short* Wo   = (unsigned short*)alloc((size_t)L_DEPTH * 768 * 768 * 2);
    unsigned short* Wm1  = (unsigned short*)alloc((size_t)L_DEPTH * 3072 * 768 * 2);
    unsigned short* Wm2  = (unsigned short*)alloc((size_t)L_DEPTH * 768 * 3072 * 2);
    unsigned short* CW   = (unsigned short*)alloc((size_t)768 * 768 * 2);
    unsigned short* AIM  = (unsigned short*)alloc((size_t)MPE * 768 * 2);
    float*          PE   = (float*)alloc((size_t)MPE * 768 * 4);
    float*          TOK  = (float*)alloc((size_t)MPAD * 768 * 4);
    unsigned short* HB   = (unsigned short*)alloc((size_t)MPAD * 768 * 2);
    unsigned short* QKV  = (unsigned short*)alloc((size_t)MPAD * 2304 * 2);
    unsigned short* PRB  = (unsigned short*)alloc((size_t)BB * NHEAD * NTOK * PSTR * 2);
    unsigned short* CTX  = (unsigned short*)alloc((size_t)MPAD * 768 * 2);
    unsigned short* MID  = (unsigned short*)alloc((size_t)MPAD * 3072 * 2);
    float*          CLS  = (float*)alloc((size_t)BB * 768 * 4);
    float*          MDH  = (float*)alloc((size_t)BB * 3072 * 4);
    if ((size_t)(p - (char*)d_ws) > ws_size) return;   // ws too small: fail loud

    // ---- weight prep (bf16, transposed to [N][K]) ----
    tconv<<<dim3(24, 24, L_DEPTH), 256, 0, stream>>>(wq, Wqkv, 768, 768, 0,    2304);
    tconv<<<dim3(24, 24, L_DEPTH), 256, 0, stream>>>(wk, Wqkv, 768, 768, 768,  2304);
    tconv<<<dim3(24, 24, L_DEPTH), 256, 0, stream>>>(wv, Wqkv, 768, 768, 1536, 2304);
    tconv<<<dim3(24, 24, L_DEPTH), 256, 0, stream>>>(wo_w, Wo, 768, 768, 0, 768);
    tconv<<<dim3(96, 24, L_DEPTH), 256, 0, stream>>>(mlp1_w, Wm1, 768, 3072, 0, 3072);
    tconv<<<dim3(24, 96, L_DEPTH), 256, 0, stream>>>(mlp2_w, Wm2, 3072, 768, 0, 768);
    cvt_bf16<<<2304, 256, 0, stream>>>(conv_w, CW, 768 * 768);  // already [out][in] = [N][K]

    // ---- patch embed ----
    im2col_k<<<(MPE * 768) / 256, 256, 0, stream>>>(x, AIM);
    gemm128<3><<<dim3(6, MPE / 128), 256, 0, stream>>>(AIM, CW, conv_b, nullptr, PE, MPE, 768, 768);
    assemble_tok<<<(MTOK * 768) / 256, 256, 0, stream>>>(PE, cls_tok, pos, TOK);

    // ---- transformer layers ----
    for (int l = 0; l < L_DEPTH; ++l) {
        ln_bf16<<<MTOK, 256, 0, stream>>>(TOK, ln1_w + (size_t)l * 768, ln1_b + (size_t)l * 768, HB);
        gemm128<0><<<dim3(18, MPAD / 128), 256, 0, stream>>>(
            HB, Wqkv + (size_t)l * 2304 * 768, nullptr, nullptr, QKV, MPAD, 2304, 768);
        attn_softmax<<<dim3(7, BB * NHEAD), 256, 0, stream>>>(QKV, PRB);
        attn_ctx<<<dim3(7, BB * NHEAD), 256, 0, stream>>>(QKV, PRB, CTX);
        gemm128<2><<<dim3(6, MPAD / 128), 256, 0, stream>>>(
            CTX, Wo + (size_t)l * 768 * 768, wo_b + (size_t)l * 768, TOK, TOK, MPAD, 768, 768);
        ln_bf16<<<MTOK, 256, 0, stream>>>(TOK, ln2_w + (size_t)l * 768, ln2_b + (size_t)l * 768, HB);
        gemm128<1><<<dim3(24, MPAD / 128), 256, 0, stream>>>(
            HB, Wm1 + (size_t)l * 3072 * 768, mlp1_b + (size_t)l * 3072, nullptr, MID, MPAD, 3072, 768);
        gemm128<2><<<dim3(6, MPAD / 128), 256, 0, stream>>>(
            MID, Wm2 + (size_t)l * 768 * 3072, mlp2_b + (size_t)l * 768, TOK, TOK, MPAD, 768, 3072);
    }

    // ---- head ----
    head_ln<<<BB, 256, 0, stream>>>(TOK, fnorm_w, fnorm_b, hln_w, hln_b, CLS);
    head_mlp1<<<dim3(12, BB), 256, 0, stream>>>(CLS, h1_w, h1_b, MDH);
    head_mlp2<<<BB * 2, 256, 0, stream>>>(MDH, h2_w, h2_b, (float*)d_out);
}

// Round 2
// 3892.737 us; speedup vs baseline: 2.3466x; 2.3466x over previous
//
#include <hip/hip_runtime.h>
#include <hip/hip_bf16.h>
#include <stdint.h>

// ---- model dims (ViT-Base/16, B=32) ----
#define L_DEPTH 12
#define DM      768
#define NHEAD   12
#define DK      64
#define DMLP    3072
#define BB      32
#define NTOK    197
#define NPATCH  196
#define MTOK    (BB*NTOK)     // 6304
#define MPAD    6400          // padded to 128 multiple
#define MPE     (BB*NPATCH)   // 6272 = 49*128

typedef __attribute__((ext_vector_type(8))) short short8;
typedef __attribute__((ext_vector_type(4))) float f4;

__device__ __forceinline__ float bf2f(unsigned short u) {
    union { float f; unsigned int i; } v; v.i = ((unsigned int)u) << 16; return v.f;
}
__device__ __forceinline__ unsigned short f2bf(float f) {
    union { float f; unsigned int i; } v; v.f = f;
    unsigned int i = v.i;
    i += 0x7fffu + ((i >> 16) & 1u);   // round-to-nearest-even
    return (unsigned short)(i >> 16);
}
__device__ __forceinline__ float gelu_f(float x) {
    return 0.5f * x * (1.0f + erff(x * 0.7071067811865475f));
}

// ---------------------------------------------------------------------------
// fp32 -> bf16 flat convert
__global__ void cvt_bf16(const float* __restrict__ src, unsigned short* __restrict__ dst, int n) {
    int i = blockIdx.x * 256 + threadIdx.x;
    if (i < n) dst[i] = f2bf(src[i]);
}

// transpose-convert: src fp32 [K][Nsrc] (per layer, z=layer) -> dst bf16 rows
// [row_off, row_off+Nsrc) of a [Ntot][K] matrix (per layer stride Ntot*K).
__global__ void tconv(const float* __restrict__ src, unsigned short* __restrict__ dst,
                      int K, int Nsrc, int row_off, int Ntot) {
    const int l = blockIdx.z;
    src += (size_t)l * K * Nsrc;
    dst += (size_t)l * Ntot * K + (size_t)row_off * K;
    __shared__ float t[32][33];
    const int tid = threadIdx.x;
    const int tx = tid & 31, ty = tid >> 5;          // 32 x 8
    const int n0 = blockIdx.x * 32, k0 = blockIdx.y * 32;
#pragma unroll
    for (int u = 0; u < 4; ++u) {
        int k = k0 + ty + u * 8;
        t[ty + u * 8][tx] = src[(size_t)k * Nsrc + n0 + tx];
    }
    __syncthreads();
#pragma unroll
    for (int u = 0; u < 4; ++u) {
        int n = n0 + ty + u * 8;
        dst[(size_t)n * K + k0 + tx] = f2bf(t[tx][ty + u * 8]);
    }
}

// im2col for patch embed
__global__ void im2col_k(const float* __restrict__ x, unsigned short* __restrict__ A) {
    int idx = blockIdx.x * 256 + threadIdx.x;          // < 6272*768
    int k = idx % DM, row = idx / DM;
    int b = row / NPATCH, p = row % NPATCH;
    int py = p / 14, px = p % 14;
    int c = k >> 8, rem = k & 255, i = rem >> 4, j = rem & 15;
    float v = x[(((size_t)b * 3 + c) * 224 + py * 16 + i) * 224 + px * 16 + j];
    A[idx] = f2bf(v);
}

// tok[b][n][d] = (n==0 ? cls : pe[b*196+n-1]) + pos[n]
__global__ void assemble_tok(const float* __restrict__ pe, const float* __restrict__ cls_t,
                             const float* __restrict__ pos, float* __restrict__ tok) {
    int idx = blockIdx.x * 256 + threadIdx.x;          // < 6304*768
    int d = idx % DM, row = idx / DM;
    int b = row / NTOK, n = row % NTOK;
    float v = (n == 0) ? cls_t[d] : pe[((size_t)b * NPATCH + n - 1) * DM + d];
    tok[idx] = v + pos[(size_t)n * DM + d];
}

// ---------------------------------------------------------------------------
// 128x128 bf16 MFMA GEMM, BK=32, 4 waves, 4x4 mfma_f32_16x16x32_bf16 per wave.
// A [M][K] bf16 row-major, Bt [N][K] bf16 row-major (= B transposed).
// EPI: 0 plain->bf16 ; 1 bias+gelu->bf16 ; 2 bias+res->fp32 ; 3 bias+gelu->fp32
template <int EPI>
__global__ __launch_bounds__(256, 2)
void gemm128(const unsigned short* __restrict__ A, const unsigned short* __restrict__ Bt,
             const float* __restrict__ bias, const float* res,
             void* Cout, int M, int N, int K) {
    __shared__ __align__(16) unsigned short As[128 * 32];
    __shared__ __align__(16) unsigned short Bs[128 * 32];
    const int tid = threadIdx.x;
    const int lane = tid & 63, wave = tid >> 6;
    const int wm = wave >> 1, wn = wave & 1;
    const int lr = lane & 15, quad = lane >> 4;
    const int bm = blockIdx.y * 128, bn = blockIdx.x * 128;

    f4 acc[4][4];
#pragma unroll
    for (int i = 0; i < 4; ++i)
#pragma unroll
        for (int j = 0; j < 4; ++j) acc[i][j] = (f4){0.f, 0.f, 0.f, 0.f};

    for (int k0 = 0; k0 < K; k0 += 32) {
#pragma unroll
        for (int u = 0; u < 2; ++u) {
            int c = tid + u * 256;               // 512 16B-chunks per 8KB tile
            int row = c >> 2, kc = c & 3;
            *(short8*)&As[c * 8] = *(const short8*)(A + (size_t)(bm + row) * K + k0 + kc * 8);
            *(short8*)&Bs[c * 8] = *(const short8*)(Bt + (size_t)(bn + row) * K + k0 + kc * 8);
        }
        __syncthreads();
        short8 af[4], bfr[4];
#pragma unroll
        for (int i = 0; i < 4; ++i)
            af[i] = *(const short8*)&As[(wm * 64 + i * 16 + lr) * 32 + quad * 8];
#pragma unroll
        for (int j = 0; j < 4; ++j)
            bfr[j] = *(const short8*)&Bs[(wn * 64 + j * 16 + lr) * 32 + quad * 8];
#pragma unroll
        for (int i = 0; i < 4; ++i)
#pragma unroll
            for (int j = 0; j < 4; ++j)
                acc[i][j] = __builtin_amdgcn_mfma_f32_16x16x32_bf16(af[i], bfr[j], acc[i][j], 0, 0, 0);
        __syncthreads();
    }

#pragma unroll
    for (int i = 0; i < 4; ++i)
#pragma unroll
        for (int j = 0; j < 4; ++j)
#pragma unroll
            for (int r = 0; r < 4; ++r) {
                int row = bm + wm * 64 + i * 16 + quad * 4 + r;
                int col = bn + wn * 64 + j * 16 + lr;
                float v = acc[i][j][r];
                if (EPI == 1 || EPI == 2 || EPI == 3) v += bias[col];
                if (EPI == 1 || EPI == 3) v = gelu_f(v);
                if (EPI == 2) v += res[(size_t)row * N + col];
                if (EPI == 0 || EPI == 1)
                    ((unsigned short*)Cout)[(size_t)row * N + col] = f2bf(v);
                else
                    ((float*)Cout)[(size_t)row * N + col] = v;
            }
}

// ---------------------------------------------------------------------------
// LayerNorm (768) fp32 in -> bf16 out, one block per row
__global__ __launch_bounds__(256)
void ln_bf16(const float* __restrict__ x, const float* __restrict__ w,
             const float* __restrict__ b, unsigned short* __restrict__ out) {
    __shared__ float red[8];
    const int tid = threadIdx.x;
    const size_t row = blockIdx.x;
    const float* xr = x + row * DM;
    float v0 = xr[tid], v1 = xr[tid + 256], v2 = xr[tid + 512];
    float s = v0 + v1 + v2, s2 = v0 * v0 + v1 * v1 + v2 * v2;
    for (int o = 32; o > 0; o >>= 1) { s += __shfl_down(s, o); s2 += __shfl_down(s2, o); }
    if ((tid & 63) == 0) { red[(tid >> 6) * 2] = s; red[(tid >> 6) * 2 + 1] = s2; }
    __syncthreads();
    s = red[0] + red[2] + red[4] + red[6];
    s2 = red[1] + red[3] + red[5] + red[7];
    float mean = s * (1.f / DM);
    float rstd = rsqrtf(s2 * (1.f / DM) - mean * mean + 1e-5f);
    out[row * DM + tid]       = f2bf((v0 - mean) * rstd * w[tid]       + b[tid]);
    out[row * DM + tid + 256] = f2bf((v1 - mean) * rstd * w[tid + 256] + b[tid + 256]);
    out[row * DM + tid + 512] = f2bf((v2 - mean) * rstd * w[tid + 512] + b[tid + 512]);
}

// ---------------------------------------------------------------------------
// Fused MFMA attention: one workgroup per (b,h). 4 waves; each wave processes
// 16-row Q strips. QK^T and PV via mfma_f32_16x16x32_bf16; softmax in regs
// with deferred normalization; P goes C-layout -> LDS -> A-layout.
#define ASTR 72     // Qs/Ks row stride (bf16 elems), 144 B
#define VSTR 232    // Vt/Ps row stride (bf16 elems), 464 B
#define MP   208    // padded token count (13*16)

__global__ __launch_bounds__(256)
void attn_fused(const unsigned short* __restrict__ qkv, unsigned short* __restrict__ ctx) {
    __shared__ __align__(16) unsigned short Qs[MP * ASTR];
    __shared__ __align__(16) unsigned short Ks[MP * ASTR];
    __shared__ __align__(16) unsigned short Vt[64 * VSTR];
    __shared__ __align__(16) unsigned short Ps[4][16 * VSTR];
    const int tid = threadIdx.x;
    const int lane = tid & 63, wave = tid >> 6;
    const int lr = lane & 15, quad = lane >> 4;
    const int bh = blockIdx.x;
    const int b = bh / NHEAD, h = bh % NHEAD;
    const size_t rowbase = (size_t)b * NTOK * 2304 + (size_t)h * 64;

    // zero pad regions (disjoint from staged regions; no barrier needed yet)
    for (int e = tid; e < 64 * (224 - NTOK); e += 256) {   // Vt cols 197..223
        int r = e / (224 - NTOK), c = NTOK + e % (224 - NTOK);
        Vt[r * VSTR + c] = 0;
    }
    for (int e = tid; e < 64 * 16; e += 256) {             // Ps cols 208..223 (all 64 rows)
        int r = e >> 4, c = MP + (e & 15);
        ((unsigned short*)Ps)[r * VSTR + c] = 0;
    }
    // stage Q,K: [MP][ASTR], rows >=197 zeroed
    const short8 z8 = {0, 0, 0, 0, 0, 0, 0, 0};
    for (int c = tid; c < MP * 8; c += 256) {
        int row = c >> 3, d0 = (c & 7) * 8;
        short8 q = z8, k = z8;
        if (row < NTOK) {
            const size_t g = rowbase + (size_t)row * 2304 + d0;
            q = *(const short8*)(qkv + g);
            k = *(const short8*)(qkv + g + 768);
        }
        *(short8*)&Qs[row * ASTR + d0] = q;
        *(short8*)&Ks[row * ASTR + d0] = k;
    }
    // stage V transposed: Vt[d][m] = V[m][d]
    for (int c = tid; c < NTOK * 8; c += 256) {
        int m = c >> 3, d0 = (c & 7) * 8;
        short8 v = *(const short8*)(qkv + rowbase + 1536 + (size_t)m * 2304 + d0);
#pragma unroll
        for (int u = 0; u < 8; ++u) Vt[(d0 + u) * VSTR + m] = v[u];
    }
    __syncthreads();

    for (int it = 0; it < 4; ++it) {
        const int strip = wave + it * 4;       // 0..15
        const bool valid = strip < 13;
        float invl[4];
        if (valid) {
            const int n0 = strip * 16;
            const short8 a0 = *(const short8*)&Qs[(n0 + lr) * ASTR + quad * 8];
            const short8 a1 = *(const short8*)&Qs[(n0 + lr) * ASTR + 32 + quad * 8];
            f4 acc[13];
#pragma unroll
            for (int t = 0; t < 13; ++t) acc[t] = (f4){0.f, 0.f, 0.f, 0.f};
#pragma unroll
            for (int t = 0; t < 13; ++t) {
                short8 b0 = *(const short8*)&Ks[(t * 16 + lr) * ASTR + quad * 8];
                short8 b1 = *(const short8*)&Ks[(t * 16 + lr) * ASTR + 32 + quad * 8];
                acc[t] = __builtin_amdgcn_mfma_f32_16x16x32_bf16(a0, b0, acc[t], 0, 0, 0);
                acc[t] = __builtin_amdgcn_mfma_f32_16x16x32_bf16(a1, b1, acc[t], 0, 0, 0);
            }
            // softmax over 208 cols (masked >=197), rows = quad*4 + rr
            float mx[4] = {-3e38f, -3e38f, -3e38f, -3e38f};
#pragma unroll
            for (int t = 0; t < 13; ++t) {
                bool maskc = (t == 12) && (lr >= 5);
#pragma unroll
                for (int rr = 0; rr < 4; ++rr) {
                    float v = maskc ? -3e38f : acc[t][rr] * 0.125f;
                    acc[t][rr] = v;
                    mx[rr] = fmaxf(mx[rr], v);
                }
            }
#pragma unroll
            for (int rr = 0; rr < 4; ++rr) {
                mx[rr] = fmaxf(mx[rr], __shfl_xor(mx[rr], 1, 16));
                mx[rr] = fmaxf(mx[rr], __shfl_xor(mx[rr], 2, 16));
                mx[rr] = fmaxf(mx[rr], __shfl_xor(mx[rr], 4, 16));
                mx[rr] = fmaxf(mx[rr], __shfl_xor(mx[rr], 8, 16));
            }
            float sm[4] = {0.f, 0.f, 0.f, 0.f};
#pragma unroll
            for (int t = 0; t < 13; ++t)
#pragma unroll
                for (int rr = 0; rr < 4; ++rr) {
                    float pv = __expf(acc[t][rr] - mx[rr]);
                    acc[t][rr] = pv;
                    sm[rr] += pv;
                }
#pragma unroll
            for (int rr = 0; rr < 4; ++rr) {
                sm[rr] += __shfl_xor(sm[rr], 1, 16);
                sm[rr] += __shfl_xor(sm[rr], 2, 16);
                sm[rr] += __shfl_xor(sm[rr], 4, 16);
                sm[rr] += __shfl_xor(sm[rr], 8, 16);
                invl[rr] = 1.f / sm[rr];
            }
            // write P (unnormalized, bf16) to per-wave LDS strip
            unsigned short* pw = &Ps[wave][0];
#pragma unroll
            for (int t = 0; t < 13; ++t)
#pragma unroll
                for (int rr = 0; rr < 4; ++rr)
                    pw[(quad * 4 + rr) * VSTR + t * 16 + lr] = f2bf(acc[t][rr]);
        }
        __syncthreads();
        if (valid) {
            f4 accc[4];
#pragma unroll
            for (int t = 0; t < 4; ++t) accc[t] = (f4){0.f, 0.f, 0.f, 0.f};
#pragma unroll
            for (int s = 0; s < 7; ++s) {
                short8 pa = *(const short8*)&Ps[wave][lr * VSTR + s * 32 + quad * 8];
#pragma unroll
                for (int t = 0; t < 4; ++t) {
                    short8 vb = *(const short8*)&Vt[(t * 16 + lr) * VSTR + s * 32 + quad * 8];
                    accc[t] = __builtin_amdgcn_mfma_f32_16x16x32_bf16(pa, vb, accc[t], 0, 0, 0);
                }
            }
            const int n0 = strip * 16;
#pragma unroll
            for (int t = 0; t < 4; ++t)
#pragma unroll
                for (int rr = 0; rr < 4; ++rr) {
                    int n = n0 + quad * 4 + rr;
                    if (n < NTOK)
                        ctx[((size_t)(b * NTOK + n)) * DM + h * 64 + t * 16 + lr] =
                            f2bf(accc[t][rr] * invl[rr]);
                }
        }
        __syncthreads();
    }
}

// ---------------------------------------------------------------------------
// head: fnorm-LN then hln-LN on cls rows -> fp32 [32][768]
__global__ __launch_bounds__(256)
void head_ln(const float* __restrict__ tok, const float* __restrict__ fw, const float* __restrict__ fb,
             const float* __restrict__ hw, const float* __restrict__ hb, float* __restrict__ cls) {
    __shared__ float red[8];
    const int tid = threadIdx.x;
    const float* xr = tok + (size_t)blockIdx.x * NTOK * DM;   // n==0 row
    float v0 = xr[tid], v1 = xr[tid + 256], v2 = xr[tid + 512];
    float s = v0 + v1 + v2, s2 = v0 * v0 + v1 * v1 + v2 * v2;
    for (int o = 32; o > 0; o >>= 1) { s += __shfl_down(s, o); s2 += __shfl_down(s2, o); }
    if ((tid & 63) == 0) { red[(tid >> 6) * 2] = s; red[(tid >> 6) * 2 + 1] = s2; }
    __syncthreads();
    s = red[0] + red[2] + red[4] + red[6];
    s2 = red[1] + red[3] + red[5] + red[7];
    float mean = s * (1.f / DM), rstd = rsqrtf(s2 * (1.f / DM) - mean * mean + 1e-5f);
    v0 = (v0 - mean) * rstd * fw[tid]       + fb[tid];
    v1 = (v1 - mean) * rstd * fw[tid + 256] + fb[tid + 256];
    v2 = (v2 - mean) * rstd * fw[tid + 512] + fb[tid + 512];
    __syncthreads();
    s = v0 + v1 + v2; s2 = v0 * v0 + v1 * v1 + v2 * v2;
    for (int o = 32; o > 0; o >>= 1) { s += __shfl_down(s, o); s2 += __shfl_down(s2, o); }
    if ((tid & 63) == 0) { red[(tid >> 6) * 2] = s; red[(tid >> 6) * 2 + 1] = s2; }
    __syncthreads();
    s = red[0] + red[2] + red[4] + red[6];
    s2 = red[1] + red[3] + red[5] + red[7];
    mean = s * (1.f / DM); rstd = rsqrtf(s2 * (1.f / DM) - mean * mean + 1e-5f);
    float* cr = cls + (size_t)blockIdx.x * DM;
    cr[tid]       = (v0 - mean) * rstd * hw[tid]       + hb[tid];
    cr[tid + 256] = (v1 - mean) * rstd * hw[tid + 256] + hb[tid + 256];
    cr[tid + 512] = (v2 - mean) * rstd * hw[tid + 512] + hb[tid + 512];
}

__global__ __launch_bounds__(256)
void head_mlp1(const float* __restrict__ cls, const float* __restrict__ w,
               const float* __restrict__ bias, float* __restrict__ outv) {
    __shared__ float cl[DM];
    const int tid = threadIdx.x;
    const int b = blockIdx.y;
    const int col = blockIdx.x * 256 + tid;
    for (int e = tid; e < DM; e += 256) cl[e] = cls[(size_t)b * DM + e];
    __syncthreads();
    float s = bias[col];
    for (int k = 0; k < DM; ++k) s += cl[k] * w[(size_t)k * DMLP + col];
    outv[(size_t)b * DMLP + col] = gelu_f(s);
}

__global__ __launch_bounds__(256)
void head_mlp2(const float* __restrict__ midh, const float* __restrict__ w,
               const float* __restrict__ bias, float* __restrict__ out) {
    __shared__ float red[256];
    const int tid = threadIdx.x;
    const int b = blockIdx.x >> 1, c = blockIdx.x & 1;
    float s = 0.f;
    for (int k = tid; k < DMLP; k += 256) s += midh[(size_t)b * DMLP + k] * w[(size_t)k * 2 + c];
    red[tid] = s;
    __syncthreads();
    for (int o = 128; o > 0; o >>= 1) { if (tid < o) red[tid] += red[tid + o]; __syncthreads(); }
    if (tid == 0) out[blockIdx.x] = red[0] + bias[c];
}

// ---------------------------------------------------------------------------
extern "C" void kernel_launch(void* const* d_in, const int* in_sizes, int n_in,
                              void* d_out, int out_size, void* d_ws, size_t ws_size,
                              hipStream_t stream) {
    if (n_in < 26) return;
    const float* x       = (const float*)d_in[0];
    const float* conv_w  = (const float*)d_in[1];
    const float* conv_b  = (const float*)d_in[2];
    const float* cls_tok = (const float*)d_in[3];
    const float* pos     = (const float*)d_in[4];
    const float* ln1_w   = (const float*)d_in[5];
    const float* ln1_b   = (const float*)d_in[6];
    const float* wq      = (const float*)d_in[7];
    const float* wk      = (const float*)d_in[8];
    const float* wv      = (const float*)d_in[9];
    const float* wo_w    = (const float*)d_in[10];
    const float* wo_b    = (const float*)d_in[11];
    const float* ln2_w   = (const float*)d_in[12];
    const float* ln2_b   = (const float*)d_in[13];
    const float* mlp1_w  = (const float*)d_in[14];
    const float* mlp1_b  = (const float*)d_in[15];
    const float* mlp2_w  = (const float*)d_in[16];
    const float* mlp2_b  = (const float*)d_in[17];
    const float* fnorm_w = (const float*)d_in[18];
    const float* fnorm_b = (const float*)d_in[19];
    const float* hln_w   = (const float*)d_in[20];
    const float* hln_b   = (const float*)d_in[21];
    const float* h1_w    = (const float*)d_in[22];
    const float* h1_b    = (const float*)d_in[23];
    const float* h2_w    = (const float*)d_in[24];
    const float* h2_b    = (const float*)d_in[25];

    char* p = (char*)d_ws;
    auto alloc = [&](size_t bytes) -> char* {
        char* r = p; p += (bytes + 255) & ~(size_t)255; return r;
    };
    unsigned short* Wqkv = (unsigned short*)alloc((size_t)L_DEPTH * 2304 * 768 * 2);
    unsigned short* Wo   = (unsigned short*)alloc((size_t)L_DEPTH * 768 * 768 * 2);
    unsigned short* Wm1  = (unsigned short*)alloc((size_t)L_DEPTH * 3072 * 768 * 2);
    unsigned short* Wm2  = (unsigned short*)alloc((size_t)L_DEPTH * 768 * 3072 * 2);
    unsigned short* CW   = (unsigned short*)alloc((size_t)768 * 768 * 2);
    unsigned short* AIM  = (unsigned short*)alloc((size_t)MPE * 768 * 2);
    float*          PE   = (float*)alloc((size_t)MPE * 768 * 4);
    float*          TOK  = (float*)alloc((size_t)MPAD * 768 * 4);
    unsigned short* HB   = (unsigned short*)alloc((size_t)MPAD * 768 * 2);
    unsigned short* QKV  = (unsigned short*)alloc((size_t)MPAD * 2304 * 2);
    unsigned short* CTX  = (unsigned short*)alloc((size_t)MPAD * 768 * 2);
    unsigned short* MID  = (unsigned short*)alloc((size_t)MPAD * 3072 * 2);
    float*          CLS  = (float*)alloc((size_t)BB * 768 * 4);
    float*          MDH  = (float*)alloc((size_t)BB * 3072 * 4);
    if ((size_t)(p - (char*)d_ws) > ws_size) return;   // ws too small: fail loud

    // ---- weight prep (bf16, transposed to [N][K]) ----
    tconv<<<dim3(24, 24, L_DEPTH), 256, 0, stream>>>(wq, Wqkv, 768, 768, 0,    2304);
    tconv<<<dim3(24, 24, L_DEPTH), 256, 0, stream>>>(wk, Wqkv, 768, 768, 768,  2304);
    tconv<<<dim3(24, 24, L_DEPTH), 256, 0, stream>>>(wv, Wqkv, 768, 768, 1536, 2304);
    tconv<<<dim3(24, 24, L_DEPTH), 256, 0, stream>>>(wo_w, Wo, 768, 768, 0, 768);
    tconv<<<dim3(96, 24, L_DEPTH), 256, 0, stream>>>(mlp1_w, Wm1, 768, 3072, 0, 3072);
    tconv<<<dim3(24, 96, L_DEPTH), 256, 0, stream>>>(mlp2_w, Wm2, 3072, 768, 0, 768);
    cvt_bf16<<<2304, 256, 0, stream>>>(conv_w, CW, 768 * 768);  // already [out][in] = [N][K]

    // ---- patch embed ----
    im2col_k<<<(MPE * 768) / 256, 256, 0, stream>>>(x, AIM);
    gemm128<3><<<dim3(6, MPE / 128), 256, 0, stream>>>(AIM, CW, conv_b, nullptr, PE, MPE, 768, 768);
    assemble_tok<<<(MTOK * 768) / 256, 256, 0, stream>>>(PE, cls_tok, pos, TOK);

    // ---- transformer layers ----
    for (int l = 0; l < L_DEPTH; ++l) {
        ln_bf16<<<MTOK, 256, 0, stream>>>(TOK, ln1_w + (size_t)l * 768, ln1_b + (size_t)l * 768, HB);
        gemm128<0><<<dim3(18, MPAD / 128), 256, 0, stream>>>(
            HB, Wqkv + (size_t)l * 2304 * 768, nullptr, nullptr, QKV, MPAD, 2304, 768);
        attn_fused<<<BB * NHEAD, 256, 0, stream>>>(QKV, CTX);
        gemm128<2><<<dim3(6, MPAD / 128), 256, 0, stream>>>(
            CTX, Wo + (size_t)l * 768 * 768, wo_b + (size_t)l * 768, TOK, TOK, MPAD, 768, 768);
        ln_bf16<<<MTOK, 256, 0, stream>>>(TOK, ln2_w + (size_t)l * 768, ln2_b + (size_t)l * 768, HB);
        gemm128<1><<<dim3(24, MPAD / 128), 256, 0, stream>>>(
            HB, Wm1 + (size_t)l * 3072 * 768, mlp1_b + (size_t)l * 3072, nullptr, MID, MPAD, 3072, 768);
        gemm128<2><<<dim3(6, MPAD / 128), 256, 0, stream>>>(
            MID, Wm2 + (size_t)l * 768 * 3072, mlp2_b + (size_t)l * 768, TOK, TOK, MPAD, 768, 3072);
    }

    // ---- head ----
    head_ln<<<BB, 256, 0, stream>>>(TOK, fnorm_w, fnorm_b, hln_w, hln_b, CLS);
    head_mlp1<<<dim3(12, BB), 256, 0, stream>>>(CLS, h1_w, h1_b, MDH);
    head_mlp2<<<BB * 2, 256, 0, stream>>>(MDH, h2_w, h2_b, (float*)d_out);
}

// Round 3
// 3799.676 us; speedup vs baseline: 2.4040x; 1.0245x over previous
//
#include <hip/hip_runtime.h>
#include <hip/hip_bf16.h>
#include <stdint.h>

// ---- model dims (ViT-Base/16, B=32) ----
#define L_DEPTH 12
#define DM      768
#define NHEAD   12
#define DK      64
#define DMLP    3072
#define BB      32
#define NTOK    197
#define NPATCH  196
#define MTOK    (BB*NTOK)     // 6304
#define MPAD    6400          // padded to 128 multiple
#define MPE     (BB*NPATCH)   // 6272 = 49*128

typedef __attribute__((ext_vector_type(8))) short short8;
typedef __attribute__((ext_vector_type(4))) float f4;

#define AS1C(p) ((const __attribute__((address_space(1))) void*)(p))
#define AS3(p)  ((__attribute__((address_space(3))) void*)(p))

__device__ __forceinline__ float bf2f(unsigned short u) {
    union { float f; unsigned int i; } v; v.i = ((unsigned int)u) << 16; return v.f;
}
__device__ __forceinline__ unsigned short f2bf(float f) {
    union { float f; unsigned int i; } v; v.f = f;
    unsigned int i = v.i;
    i += 0x7fffu + ((i >> 16) & 1u);   // round-to-nearest-even
    return (unsigned short)(i >> 16);
}
__device__ __forceinline__ float gelu_f(float x) {
    return 0.5f * x * (1.0f + erff(x * 0.7071067811865475f));
}

// ---------------------------------------------------------------------------
// fp32 -> bf16 flat convert
__global__ void cvt_bf16(const float* __restrict__ src, unsigned short* __restrict__ dst, int n) {
    int i = blockIdx.x * 256 + threadIdx.x;
    if (i < n) dst[i] = f2bf(src[i]);
}

// transpose-convert: src fp32 [K][Nsrc] (per layer, z=layer) -> dst bf16 rows
// [row_off, row_off+Nsrc) of a [Ntot][K] matrix (per layer stride Ntot*K).
__global__ void tconv(const float* __restrict__ src, unsigned short* __restrict__ dst,
                      int K, int Nsrc, int row_off, int Ntot) {
    const int l = blockIdx.z;
    src += (size_t)l * K * Nsrc;
    dst += (size_t)l * Ntot * K + (size_t)row_off * K;
    __shared__ float t[32][33];
    const int tid = threadIdx.x;
    const int tx = tid & 31, ty = tid >> 5;          // 32 x 8
    const int n0 = blockIdx.x * 32, k0 = blockIdx.y * 32;
#pragma unroll
    for (int u = 0; u < 4; ++u) {
        int k = k0 + ty + u * 8;
        t[ty + u * 8][tx] = src[(size_t)k * Nsrc + n0 + tx];
    }
    __syncthreads();
#pragma unroll
    for (int u = 0; u < 4; ++u) {
        int n = n0 + ty + u * 8;
        dst[(size_t)n * K + k0 + tx] = f2bf(t[tx][ty + u * 8]);
    }
}

// im2col for patch embed
__global__ void im2col_k(const float* __restrict__ x, unsigned short* __restrict__ A) {
    int idx = blockIdx.x * 256 + threadIdx.x;          // < 6272*768
    int k = idx % DM, row = idx / DM;
    int b = row / NPATCH, p = row % NPATCH;
    int py = p / 14, px = p % 14;
    int c = k >> 8, rem = k & 255, i = rem >> 4, j = rem & 15;
    float v = x[(((size_t)b * 3 + c) * 224 + py * 16 + i) * 224 + px * 16 + j];
    A[idx] = f2bf(v);
}

// tok[b][n][d] = (n==0 ? cls : pe[b*196+n-1]) + pos[n]
__global__ void assemble_tok(const float* __restrict__ pe, const float* __restrict__ cls_t,
                             const float* __restrict__ pos, float* __restrict__ tok) {
    int idx = blockIdx.x * 256 + threadIdx.x;          // < 6304*768
    int d = idx % DM, row = idx / DM;
    int b = row / NTOK, n = row % NTOK;
    float v = (n == 0) ? cls_t[d] : pe[((size_t)b * NPATCH + n - 1) * DM + d];
    tok[idx] = v + pos[(size_t)n * DM + d];
}

// ---------------------------------------------------------------------------
// 128x128 bf16 MFMA GEMM, BK=32, 4 waves, 4x4 mfma_f32_16x16x32_bf16 per wave.
// A [M][K] bf16 row-major, Bt [N][K] bf16 row-major (= B transposed).
// Staging via global_load_lds width=16 (async, no VGPR round-trip).
// Launch: gridDim.y padded to multiple of 8; XCD swizzle groups the column
// tiles of one A row-panel onto one XCD (L2 reuse of the A panel).
// EPI: 0 plain->bf16 ; 1 bias+gelu->bf16 ; 2 bias+res->fp32 ; 3 bias+gelu->fp32
template <int EPI>
__global__ __launch_bounds__(256, 2)
void gemm128(const unsigned short* __restrict__ A, const unsigned short* __restrict__ Bt,
             const float* __restrict__ bias, const float* res,
             void* Cout, int M, int N, int K) {
    __shared__ __align__(16) unsigned short As[128 * 32];
    __shared__ __align__(16) unsigned short Bs[128 * 32];
    const int tid = threadIdx.x;
    const int lane = tid & 63, wave = tid >> 6;
    const int wm = wave >> 1, wn = wave & 1;
    const int lr = lane & 15, quad = lane >> 4;

    // XCD-aware swizzle: linear%8 selects the row-panel group so all column
    // tiles of a panel share an XCD-private L2.
    const int L = blockIdx.y * gridDim.x + blockIdx.x;
    const int xcd = L & 7, pos = L >> 3;
    const int by = xcd + 8 * (pos / gridDim.x);
    const int bx = pos % gridDim.x;
    const int bm = by * 128, bn = bx * 128;
    if (bm >= M) return;                       // padded grid tail (block-uniform)

    f4 acc[4][4];
#pragma unroll
    for (int i = 0; i < 4; ++i)
#pragma unroll
        for (int j = 0; j < 4; ++j) acc[i][j] = (f4){0.f, 0.f, 0.f, 0.f};

    for (int k0 = 0; k0 < K; k0 += 32) {
#pragma unroll
        for (int u = 0; u < 2; ++u) {
            int c = tid + u * 256;               // chunk id: this lane's 16B chunk
            int row = c >> 2, kc = c & 3;
            // wave-uniform LDS base; HW deposits lane i at base + i*16
            __builtin_amdgcn_global_load_lds(
                AS1C(A + (size_t)(bm + row) * K + k0 + kc * 8),
                AS3(&As[(wave * 64 + u * 256) * 8]), 16, 0, 0);
            __builtin_amdgcn_global_load_lds(
                AS1C(Bt + (size_t)(bn + row) * K + k0 + kc * 8),
                AS3(&Bs[(wave * 64 + u * 256) * 8]), 16, 0, 0);
        }
        __syncthreads();
        short8 af[4], bfr[4];
#pragma unroll
        for (int i = 0; i < 4; ++i)
            af[i] = *(const short8*)&As[(wm * 64 + i * 16 + lr) * 32 + quad * 8];
#pragma unroll
        for (int j = 0; j < 4; ++j)
            bfr[j] = *(const short8*)&Bs[(wn * 64 + j * 16 + lr) * 32 + quad * 8];
#pragma unroll
        for (int i = 0; i < 4; ++i)
#pragma unroll
            for (int j = 0; j < 4; ++j)
                acc[i][j] = __builtin_amdgcn_mfma_f32_16x16x32_bf16(af[i], bfr[j], acc[i][j], 0, 0, 0);
        __syncthreads();
    }

#pragma unroll
    for (int i = 0; i < 4; ++i)
#pragma unroll
        for (int j = 0; j < 4; ++j)
#pragma unroll
            for (int r = 0; r < 4; ++r) {
                int row = bm + wm * 64 + i * 16 + quad * 4 + r;
                int col = bn + wn * 64 + j * 16 + lr;
                float v = acc[i][j][r];
                if (EPI == 1 || EPI == 2 || EPI == 3) v += bias[col];
                if (EPI == 1 || EPI == 3) v = gelu_f(v);
                if (EPI == 2) v += res[(size_t)row * N + col];
                if (EPI == 0 || EPI == 1)
                    ((unsigned short*)Cout)[(size_t)row * N + col] = f2bf(v);
                else
                    ((float*)Cout)[(size_t)row * N + col] = v;
            }
}

// ---------------------------------------------------------------------------
// LayerNorm (768) fp32 in -> bf16 out, one block per row
__global__ __launch_bounds__(256)
void ln_bf16(const float* __restrict__ x, const float* __restrict__ w,
             const float* __restrict__ b, unsigned short* __restrict__ out) {
    __shared__ float red[8];
    const int tid = threadIdx.x;
    const size_t row = blockIdx.x;
    const float* xr = x + row * DM;
    float v0 = xr[tid], v1 = xr[tid + 256], v2 = xr[tid + 512];
    float s = v0 + v1 + v2, s2 = v0 * v0 + v1 * v1 + v2 * v2;
    for (int o = 32; o > 0; o >>= 1) { s += __shfl_down(s, o); s2 += __shfl_down(s2, o); }
    if ((tid & 63) == 0) { red[(tid >> 6) * 2] = s; red[(tid >> 6) * 2 + 1] = s2; }
    __syncthreads();
    s = red[0] + red[2] + red[4] + red[6];
    s2 = red[1] + red[3] + red[5] + red[7];
    float mean = s * (1.f / DM);
    float rstd = rsqrtf(s2 * (1.f / DM) - mean * mean + 1e-5f);
    out[row * DM + tid]       = f2bf((v0 - mean) * rstd * w[tid]       + b[tid]);
    out[row * DM + tid + 256] = f2bf((v1 - mean) * rstd * w[tid + 256] + b[tid + 256]);
    out[row * DM + tid + 512] = f2bf((v2 - mean) * rstd * w[tid + 512] + b[tid + 512]);
}

// ---------------------------------------------------------------------------
// Fused MFMA attention: one workgroup per (b,h). 4 waves; each wave processes
// 16-row Q strips. QK^T and PV via mfma_f32_16x16x32_bf16; softmax in regs
// with deferred normalization; P goes C-layout -> LDS -> A-layout.
#define ASTR 72     // Qs/Ks row stride (bf16 elems), 144 B
#define VSTR 232    // Vt/Ps row stride (bf16 elems), 464 B
#define MP   208    // padded token count (13*16)

__global__ __launch_bounds__(256)
void attn_fused(const unsigned short* __restrict__ qkv, unsigned short* __restrict__ ctx) {
    __shared__ __align__(16) unsigned short Qs[MP * ASTR];
    __shared__ __align__(16) unsigned short Ks[MP * ASTR];
    __shared__ __align__(16) unsigned short Vt[64 * VSTR];
    __shared__ __align__(16) unsigned short Ps[4][16 * VSTR];
    const int tid = threadIdx.x;
    const int lane = tid & 63, wave = tid >> 6;
    const int lr = lane & 15, quad = lane >> 4;
    const int bh = blockIdx.x;
    const int b = bh / NHEAD, h = bh % NHEAD;
    const size_t rowbase = (size_t)b * NTOK * 2304 + (size_t)h * 64;

    // zero pad regions (disjoint from staged regions; no barrier needed yet)
    for (int e = tid; e < 64 * (224 - NTOK); e += 256) {   // Vt cols 197..223
        int r = e / (224 - NTOK), c = NTOK + e % (224 - NTOK);
        Vt[r * VSTR + c] = 0;
    }
    for (int e = tid; e < 64 * 16; e += 256) {             // Ps cols 208..223 (all 64 rows)
        int r = e >> 4, c = MP + (e & 15);
        ((unsigned short*)Ps)[r * VSTR + c] = 0;
    }
    // stage Q,K: [MP][ASTR], rows >=197 zeroed
    const short8 z8 = {0, 0, 0, 0, 0, 0, 0, 0};
    for (int c = tid; c < MP * 8; c += 256) {
        int row = c >> 3, d0 = (c & 7) * 8;
        short8 q = z8, k = z8;
        if (row < NTOK) {
            const size_t g = rowbase + (size_t)row * 2304 + d0;
            q = *(const short8*)(qkv + g);
            k = *(const short8*)(qkv + g + 768);
        }
        *(short8*)&Qs[row * ASTR + d0] = q;
        *(short8*)&Ks[row * ASTR + d0] = k;
    }
    // stage V transposed: Vt[d][m] = V[m][d]
    for (int c = tid; c < NTOK * 8; c += 256) {
        int m = c >> 3, d0 = (c & 7) * 8;
        short8 v = *(const short8*)(qkv + rowbase + 1536 + (size_t)m * 2304 + d0);
#pragma unroll
        for (int u = 0; u < 8; ++u) Vt[(d0 + u) * VSTR + m] = v[u];
    }
    __syncthreads();

    for (int it = 0; it < 4; ++it) {
        const int strip = wave + it * 4;       // 0..15
        const bool valid = strip < 13;
        float invl[4];
        if (valid) {
            const int n0 = strip * 16;
            const short8 a0 = *(const short8*)&Qs[(n0 + lr) * ASTR + quad * 8];
            const short8 a1 = *(const short8*)&Qs[(n0 + lr) * ASTR + 32 + quad * 8];
            f4 acc[13];
#pragma unroll
            for (int t = 0; t < 13; ++t) acc[t] = (f4){0.f, 0.f, 0.f, 0.f};
#pragma unroll
            for (int t = 0; t < 13; ++t) {
                short8 b0 = *(const short8*)&Ks[(t * 16 + lr) * ASTR + quad * 8];
                short8 b1 = *(const short8*)&Ks[(t * 16 + lr) * ASTR + 32 + quad * 8];
                acc[t] = __builtin_amdgcn_mfma_f32_16x16x32_bf16(a0, b0, acc[t], 0, 0, 0);
                acc[t] = __builtin_amdgcn_mfma_f32_16x16x32_bf16(a1, b1, acc[t], 0, 0, 0);
            }
            // softmax over 208 cols (masked >=197), rows = quad*4 + rr
            float mx[4] = {-3e38f, -3e38f, -3e38f, -3e38f};
#pragma unroll
            for (int t = 0; t < 13; ++t) {
                bool maskc = (t == 12) && (lr >= 5);
#pragma unroll
                for (int rr = 0; rr < 4; ++rr) {
                    float v = maskc ? -3e38f : acc[t][rr] * 0.125f;
                    acc[t][rr] = v;
                    mx[rr] = fmaxf(mx[rr], v);
                }
            }
#pragma unroll
            for (int rr = 0; rr < 4; ++rr) {
                mx[rr] = fmaxf(mx[rr], __shfl_xor(mx[rr], 1, 16));
                mx[rr] = fmaxf(mx[rr], __shfl_xor(mx[rr], 2, 16));
                mx[rr] = fmaxf(mx[rr], __shfl_xor(mx[rr], 4, 16));
                mx[rr] = fmaxf(mx[rr], __shfl_xor(mx[rr], 8, 16));
            }
            float sm[4] = {0.f, 0.f, 0.f, 0.f};
#pragma unroll
            for (int t = 0; t < 13; ++t)
#pragma unroll
                for (int rr = 0; rr < 4; ++rr) {
                    float pv = __expf(acc[t][rr] - mx[rr]);
                    acc[t][rr] = pv;
                    sm[rr] += pv;
                }
#pragma unroll
            for (int rr = 0; rr < 4; ++rr) {
                sm[rr] += __shfl_xor(sm[rr], 1, 16);
                sm[rr] += __shfl_xor(sm[rr], 2, 16);
                sm[rr] += __shfl_xor(sm[rr], 4, 16);
                sm[rr] += __shfl_xor(sm[rr], 8, 16);
                invl[rr] = 1.f / sm[rr];
            }
            // write P (unnormalized, bf16) to per-wave LDS strip
            unsigned short* pw = &Ps[wave][0];
#pragma unroll
            for (int t = 0; t < 13; ++t)
#pragma unroll
                for (int rr = 0; rr < 4; ++rr)
                    pw[(quad * 4 + rr) * VSTR + t * 16 + lr] = f2bf(acc[t][rr]);
        }
        __syncthreads();
        if (valid) {
            f4 accc[4];
#pragma unroll
            for (int t = 0; t < 4; ++t) accc[t] = (f4){0.f, 0.f, 0.f, 0.f};
#pragma unroll
            for (int s = 0; s < 7; ++s) {
                short8 pa = *(const short8*)&Ps[wave][lr * VSTR + s * 32 + quad * 8];
#pragma unroll
                for (int t = 0; t < 4; ++t) {
                    short8 vb = *(const short8*)&Vt[(t * 16 + lr) * VSTR + s * 32 + quad * 8];
                    accc[t] = __builtin_amdgcn_mfma_f32_16x16x32_bf16(pa, vb, accc[t], 0, 0, 0);
                }
            }
            const int n0 = strip * 16;
#pragma unroll
            for (int t = 0; t < 4; ++t)
#pragma unroll
                for (int rr = 0; rr < 4; ++rr) {
                    int n = n0 + quad * 4 + rr;
                    if (n < NTOK)
                        ctx[((size_t)(b * NTOK + n)) * DM + h * 64 + t * 16 + lr] =
                            f2bf(accc[t][rr] * invl[rr]);
                }
        }
        __syncthreads();
    }
}

// ---------------------------------------------------------------------------
// head: fnorm-LN then hln-LN on cls rows -> fp32 [32][768]
__global__ __launch_bounds__(256)
void head_ln(const float* __restrict__ tok, const float* __restrict__ fw, const float* __restrict__ fb,
             const float* __restrict__ hw, const float* __restrict__ hb, float* __restrict__ cls) {
    __shared__ float red[8];
    const int tid = threadIdx.x;
    const float* xr = tok + (size_t)blockIdx.x * NTOK * DM;   // n==0 row
    float v0 = xr[tid], v1 = xr[tid + 256], v2 = xr[tid + 512];
    float s = v0 + v1 + v2, s2 = v0 * v0 + v1 * v1 + v2 * v2;
    for (int o = 32; o > 0; o >>= 1) { s += __shfl_down(s, o); s2 += __shfl_down(s2, o); }
    if ((tid & 63) == 0) { red[(tid >> 6) * 2] = s; red[(tid >> 6) * 2 + 1] = s2; }
    __syncthreads();
    s = red[0] + red[2] + red[4] + red[6];
    s2 = red[1] + red[3] + red[5] + red[7];
    float mean = s * (1.f / DM), rstd = rsqrtf(s2 * (1.f / DM) - mean * mean + 1e-5f);
    v0 = (v0 - mean) * rstd * fw[tid]       + fb[tid];
    v1 = (v1 - mean) * rstd * fw[tid + 256] + fb[tid + 256];
    v2 = (v2 - mean) * rstd * fw[tid + 512] + fb[tid + 512];
    __syncthreads();
    s = v0 + v1 + v2; s2 = v0 * v0 + v1 * v1 + v2 * v2;
    for (int o = 32; o > 0; o >>= 1) { s += __shfl_down(s, o); s2 += __shfl_down(s2, o); }
    if ((tid & 63) == 0) { red[(tid >> 6) * 2] = s; red[(tid >> 6) * 2 + 1] = s2; }
    __syncthreads();
    s = red[0] + red[2] + red[4] + red[6];
    s2 = red[1] + red[3] + red[5] + red[7];
    mean = s * (1.f / DM); rstd = rsqrtf(s2 * (1.f / DM) - mean * mean + 1e-5f);
    float* cr = cls + (size_t)blockIdx.x * DM;
    cr[tid]       = (v0 - mean) * rstd * hw[tid]       + hb[tid];
    cr[tid + 256] = (v1 - mean) * rstd * hw[tid + 256] + hb[tid + 256];
    cr[tid + 512] = (v2 - mean) * rstd * hw[tid + 512] + hb[tid + 512];
}

__global__ __launch_bounds__(256)
void head_mlp1(const float* __restrict__ cls, const float* __restrict__ w,
               const float* __restrict__ bias, float* __restrict__ outv) {
    __shared__ float cl[DM];
    const int tid = threadIdx.x;
    const int b = blockIdx.y;
    const int col = blockIdx.x * 256 + tid;
    for (int e = tid; e < DM; e += 256) cl[e] = cls[(size_t)b * DM + e];
    __syncthreads();
    float s = bias[col];
    for (int k = 0; k < DM; ++k) s += cl[k] * w[(size_t)k * DMLP + col];
    outv[(size_t)b * DMLP + col] = gelu_f(s);
}

__global__ __launch_bounds__(256)
void head_mlp2(const float* __restrict__ midh, const float* __restrict__ w,
               const float* __restrict__ bias, float* __restrict__ out) {
    __shared__ float red[256];
    const int tid = threadIdx.x;
    const int b = blockIdx.x >> 1, c = blockIdx.x & 1;
    float s = 0.f;
    for (int k = tid; k < DMLP; k += 256) s += midh[(size_t)b * DMLP + k] * w[(size_t)k * 2 + c];
    red[tid] = s;
    __syncthreads();
    for (int o = 128; o > 0; o >>= 1) { if (tid < o) red[tid] += red[tid + o]; __syncthreads(); }
    if (tid == 0) out[blockIdx.x] = red[0] + bias[c];
}

// ---------------------------------------------------------------------------
extern "C" void kernel_launch(void* const* d_in, const int* in_sizes, int n_in,
                              void* d_out, int out_size, void* d_ws, size_t ws_size,
                              hipStream_t stream) {
    if (n_in < 26) return;
    const float* x       = (const float*)d_in[0];
    const float* conv_w  = (const float*)d_in[1];
    const float* conv_b  = (const float*)d_in[2];
    const float* cls_tok = (const float*)d_in[3];
    const float* pos     = (const float*)d_in[4];
    const float* ln1_w   = (const float*)d_in[5];
    const float* ln1_b   = (const float*)d_in[6];
    const float* wq      = (const float*)d_in[7];
    const float* wk      = (const float*)d_in[8];
    const float* wv      = (const float*)d_in[9];
    const float* wo_w    = (const float*)d_in[10];
    const float* wo_b    = (const float*)d_in[11];
    const float* ln2_w   = (const float*)d_in[12];
    const float* ln2_b   = (const float*)d_in[13];
    const float* mlp1_w  = (const float*)d_in[14];
    const float* mlp1_b  = (const float*)d_in[15];
    const float* mlp2_w  = (const float*)d_in[16];
    const float* mlp2_b  = (const float*)d_in[17];
    const float* fnorm_w = (const float*)d_in[18];
    const float* fnorm_b = (const float*)d_in[19];
    const float* hln_w   = (const float*)d_in[20];
    const float* hln_b   = (const float*)d_in[21];
    const float* h1_w    = (const float*)d_in[22];
    const float* h1_b    = (const float*)d_in[23];
    const float* h2_w    = (const float*)d_in[24];
    const float* h2_b    = (const float*)d_in[25];

    char* p = (char*)d_ws;
    auto alloc = [&](size_t bytes) -> char* {
        char* r = p; p += (bytes + 255) & ~(size_t)255; return r;
    };
    unsigned short* Wqkv = (unsigned short*)alloc((size_t)L_DEPTH * 2304 * 768 * 2);
    unsigned short* Wo   = (unsigned short*)alloc((size_t)L_DEPTH * 768 * 768 * 2);
    unsigned short* Wm1  = (unsigned short*)alloc((size_t)L_DEPTH * 3072 * 768 * 2);
    unsigned short* Wm2  = (unsigned short*)alloc((size_t)L_DEPTH * 768 * 3072 * 2);
    unsigned short* CW   = (unsigned short*)alloc((size_t)768 * 768 * 2);
    unsigned short* AIM  = (unsigned short*)alloc((size_t)MPE * 768 * 2);
    float*          PE   = (float*)alloc((size_t)MPE * 768 * 4);
    float*          TOK  = (float*)alloc((size_t)MPAD * 768 * 4);
    unsigned short* HB   = (unsigned short*)alloc((size_t)MPAD * 768 * 2);
    unsigned short* QKV  = (unsigned short*)alloc((size_t)MPAD * 2304 * 2);
    unsigned short* CTX  = (unsigned short*)alloc((size_t)MPAD * 768 * 2);
    unsigned short* MID  = (unsigned short*)alloc((size_t)MPAD * 3072 * 2);
    float*          CLS  = (float*)alloc((size_t)BB * 768 * 4);
    float*          MDH  = (float*)alloc((size_t)BB * 3072 * 4);
    if ((size_t)(p - (char*)d_ws) > ws_size) return;   // ws too small: fail loud

    // ---- weight prep (bf16, transposed to [N][K]) ----
    tconv<<<dim3(24, 24, L_DEPTH), 256, 0, stream>>>(wq, Wqkv, 768, 768, 0,    2304);
    tconv<<<dim3(24, 24, L_DEPTH), 256, 0, stream>>>(wk, Wqkv, 768, 768, 768,  2304);
    tconv<<<dim3(24, 24, L_DEPTH), 256, 0, stream>>>(wv, Wqkv, 768, 768, 1536, 2304);
    tconv<<<dim3(24, 24, L_DEPTH), 256, 0, stream>>>(wo_w, Wo, 768, 768, 0, 768);
    tconv<<<dim3(96, 24, L_DEPTH), 256, 0, stream>>>(mlp1_w, Wm1, 768, 3072, 0, 3072);
    tconv<<<dim3(24, 96, L_DEPTH), 256, 0, stream>>>(mlp2_w, Wm2, 3072, 768, 0, 768);
    cvt_bf16<<<2304, 256, 0, stream>>>(conv_w, CW, 768 * 768);  // already [out][in] = [N][K]

    // grid-y padded to multiple of 8 for the XCD swizzle (tail blocks return)
    const int NYP = 56;   // ceil(50/8)*8 (also covers MPE's 49 row-panels)

    // ---- patch embed ----
    im2col_k<<<(MPE * 768) / 256, 256, 0, stream>>>(x, AIM);
    gemm128<3><<<dim3(6, NYP), 256, 0, stream>>>(AIM, CW, conv_b, nullptr, PE, MPE, 768, 768);
    assemble_tok<<<(MTOK * 768) / 256, 256, 0, stream>>>(PE, cls_tok, pos, TOK);

    // ---- transformer layers ----
    for (int l = 0; l < L_DEPTH; ++l) {
        ln_bf16<<<MTOK, 256, 0, stream>>>(TOK, ln1_w + (size_t)l * 768, ln1_b + (size_t)l * 768, HB);
        gemm128<0><<<dim3(18, NYP), 256, 0, stream>>>(
            HB, Wqkv + (size_t)l * 2304 * 768, nullptr, nullptr, QKV, MPAD, 2304, 768);
        attn_fused<<<BB * NHEAD, 256, 0, stream>>>(QKV, CTX);
        gemm128<2><<<dim3(6, NYP), 256, 0, stream>>>(
            CTX, Wo + (size_t)l * 768 * 768, wo_b + (size_t)l * 768, TOK, TOK, MPAD, 768, 768);
        ln_bf16<<<MTOK, 256, 0, stream>>>(TOK, ln2_w + (size_t)l * 768, ln2_b + (size_t)l * 768, HB);
        gemm128<1><<<dim3(24, NYP), 256, 0, stream>>>(
            HB, Wm1 + (size_t)l * 3072 * 768, mlp1_b + (size_t)l * 3072, nullptr, MID, MPAD, 3072, 768);
        gemm128<2><<<dim3(6, NYP), 256, 0, stream>>>(
            MID, Wm2 + (size_t)l * 768 * 3072, mlp2_b + (size_t)l * 768, TOK, TOK, MPAD, 768, 3072);
    }

    // ---- head ----
    head_ln<<<BB, 256, 0, stream>>>(TOK, fnorm_w, fnorm_b, hln_w, hln_b, CLS);
    head_mlp1<<<dim3(12, BB), 256, 0, stream>>>(CLS, h1_w, h1_b, MDH);
    head_mlp2<<<BB * 2, 256, 0, stream>>>(MDH, h2_w, h2_b, (float*)d_out);
}